// Round 1
// baseline (112.729 us; speedup 1.0000x reference)
//
#include <hip/hip_runtime.h>

#define BB 16
#define CC 128
#define TT 128
#define HH 128
#define BC (BB*CC)   // 2048

typedef __attribute__((ext_vector_type(8))) short bf16x8;
typedef __attribute__((ext_vector_type(4))) float f32x4;

__device__ __forceinline__ unsigned short f2bf(float f) {
  union { float f; unsigned u; } v; v.f = f;
  unsigned u = v.u;
  u += 0x7FFFu + ((u >> 16) & 1u);   // round-to-nearest-even
  return (unsigned short)(u >> 16);
}

__device__ __forceinline__ bf16x8 pack8(float4 a, float4 b) {
  bf16x8 r;
  r[0] = (short)f2bf(a.x); r[1] = (short)f2bf(a.y);
  r[2] = (short)f2bf(a.z); r[3] = (short)f2bf(a.w);
  r[4] = (short)f2bf(b.x); r[5] = (short)f2bf(b.y);
  r[6] = (short)f2bf(b.z); r[7] = (short)f2bf(b.w);
  return r;
}

// ---------------- prep: transpose + bf16-convert the weights ----------------
// W2T[n][h]    = W_thorn[128+h][n]                  (128x128)
// WcombT[n][kk]= kk<128 ? W_clone[256+kk][n] : W_clone[kk][n]   (128x256)
// WaggT[n][k]  = W_agg[k][n]                        (128x512)
__global__ __launch_bounds__(256) void prep_weights(
    const float* __restrict__ Wt, const float* __restrict__ Wc, const float* __restrict__ Wa,
    unsigned short* __restrict__ W2T, unsigned short* __restrict__ WcombT,
    unsigned short* __restrict__ WaggT) {
  int i = blockIdx.x * 256 + threadIdx.x;
  if (i < 16384) {
    int n = i >> 7, h = i & 127;
    W2T[i] = f2bf(Wt[(128 + h) * 128 + n]);
  } else if (i < 49152) {
    int j = i - 16384;
    int n = j >> 8, kk = j & 255;
    float v = (kk < 128) ? Wc[(256 + kk) * 128 + n] : Wc[kk * 128 + n];
    WcombT[j] = f2bf(v);
  } else {
    int j = i - 49152;
    int n = j >> 9, k = j & 511;
    WaggT[j] = f2bf(Wa[k * 128 + n]);
  }
}

// -------- prep: bias rows (clone@W + b) and the easy agg slices --------
__global__ __launch_bounds__(128) void prep_rows(
    const float* __restrict__ clone, const float* __restrict__ food,
    const float* __restrict__ Wt, const float* __restrict__ Wc,
    const float* __restrict__ bt, const float* __restrict__ bcl,
    float* __restrict__ cpt, float* __restrict__ cp1,
    unsigned short* __restrict__ agg) {
  int bc = blockIdx.x; int k = threadIdx.x;
  __shared__ float cl[128];
  cl[k] = clone[bc * 128 + k];
  __syncthreads();
  float s1 = bt[k], s2 = bcl[k];
  #pragma unroll 8
  for (int h = 0; h < 128; ++h) {
    float c = cl[h];
    s1 = fmaf(c, Wt[h * 128 + k], s1);
    s2 = fmaf(c, Wc[h * 128 + k], s2);
  }
  cpt[bc * 128 + k] = s1;
  cp1[bc * 128 + k] = s2;
  agg[bc * 512 + k]       = f2bf(cl[k]);
  agg[bc * 512 + 128 + k] = f2bf(food[bc * 128 + k]);
}

// ---------------- branch kernel: X = A'(128 x NKT*32) @ B'(NKT*32 x 128) ---
// thorn: NKT=4, A'=thorn_rel[b,c];  clone: NKT=8, A'=[clone_rel[b,c] | clone[b]]
// then x += biasrow;  relu;  *mask(row);  max over rows -> agg[bc][AGGOFF..+128]
template<int NKT, int AGGOFF>
__global__ __launch_bounds__(256, 2) void branch_kernel(
    const float* __restrict__ rel, const float* __restrict__ cloneA,
    const float* __restrict__ biasrow, const int* __restrict__ mask,
    const unsigned short* __restrict__ WT, unsigned short* __restrict__ agg) {
  constexpr int KW = NKT * 32 + 8;          // +8 bf16 pad -> bank spread
  __shared__ unsigned short Wlds[128][KW];
  __shared__ float biasl[128];
  __shared__ float maskl[128];
  __shared__ float redbuf[4][128];

  const int tid = threadIdx.x;
  const int wave = tid >> 6, lane = tid & 63;
  const int l16 = lane & 15, lk = lane >> 4;
  const int bc = blockIdx.x, b = bc >> 7;

  // stage transposed weight tile (bf16) into padded LDS, 16B chunks
  const int nch = 128 * NKT * 4;
  for (int i = tid; i < nch; i += 256) {
    int n = i / (NKT * 4);
    int k = (i - n * (NKT * 4)) * 8;
    uint4 v = ((const uint4*)WT)[i];
    *(uint4*)&Wlds[n][k] = v;
  }
  if (tid < 128) {
    biasl[tid] = biasrow[bc * 128 + tid];
    maskl[tid] = (float)mask[b * 128 + tid];
  }
  __syncthreads();

  // A fragments: global f32 -> bf16 regs.  A[row][k], k = kt*32 + lk*8 + e
  bf16x8 afrag[2][NKT];
  const float* Rb = rel + (size_t)bc * 16384;
  const float* Cb = cloneA + (size_t)b * 16384;
  #pragma unroll
  for (int m = 0; m < 2; ++m) {
    int row = wave * 32 + m * 16 + l16;
    #pragma unroll
    for (int kt = 0; kt < NKT; ++kt) {
      const float* src = (kt < 4) ? (Rb + row * 128 + kt * 32 + lk * 8)
                                  : (Cb + row * 128 + (kt - 4) * 32 + lk * 8);
      float4 a0 = *(const float4*)src;
      float4 a1 = *(const float4*)(src + 4);
      afrag[m][kt] = pack8(a0, a1);
    }
  }

  f32x4 acc[2][8];
  #pragma unroll
  for (int m = 0; m < 2; ++m)
    #pragma unroll
    for (int n = 0; n < 8; ++n)
      acc[m][n] = (f32x4){0.f, 0.f, 0.f, 0.f};

  #pragma unroll
  for (int n = 0; n < 8; ++n) {
    int ncol = n * 16 + l16;
    #pragma unroll
    for (int kt = 0; kt < NKT; ++kt) {
      bf16x8 bfrag = *(const bf16x8*)&Wlds[ncol][kt * 32 + lk * 8];
      acc[0][n] = __builtin_amdgcn_mfma_f32_16x16x32_bf16(afrag[0][kt], bfrag, acc[0][n], 0, 0, 0);
      acc[1][n] = __builtin_amdgcn_mfma_f32_16x16x32_bf16(afrag[1][kt], bfrag, acc[1][n], 0, 0, 0);
    }
  }

  // epilogue: bias, relu, row-mask, max over the wave's 32 rows
  float pm[8];
  #pragma unroll
  for (int n = 0; n < 8; ++n) pm[n] = 0.f;
  #pragma unroll
  for (int m = 0; m < 2; ++m) {
    #pragma unroll
    for (int j = 0; j < 4; ++j) {
      int row = wave * 32 + m * 16 + lk * 4 + j;   // C layout: row=(l>>4)*4+reg
      float msk = maskl[row];
      #pragma unroll
      for (int n = 0; n < 8; ++n) {
        float x = acc[m][n][j] + biasl[n * 16 + l16];
        x = fmaxf(x, 0.f) * msk;
        pm[n] = fmaxf(pm[n], x);
      }
    }
  }
  #pragma unroll
  for (int n = 0; n < 8; ++n) {
    float v = pm[n];
    v = fmaxf(v, __shfl_xor(v, 16));
    v = fmaxf(v, __shfl_xor(v, 32));
    if (lane < 16) redbuf[wave][n * 16 + lane] = v;
  }
  __syncthreads();
  if (tid < 128) {
    float v = fmaxf(fmaxf(redbuf[0][tid], redbuf[1][tid]),
                    fmaxf(redbuf[2][tid], redbuf[3][tid]));
    agg[bc * 512 + AGGOFF + tid] = f2bf(v);
  }
}

// ---------------- final: out = clone + relu(agg(2048x512) @ W_agg + b_agg) --
__global__ __launch_bounds__(256) void final_kernel(
    const unsigned short* __restrict__ agg, const unsigned short* __restrict__ WaggT,
    const float* __restrict__ clone, const float* __restrict__ bagg,
    float* __restrict__ out) {
  const int tid = threadIdx.x;
  const int wave = tid >> 6, lane = tid & 63;
  const int l16 = lane & 15, lk = lane >> 4;
  const int mrow = blockIdx.x * 16;

  f32x4 acc[2];
  acc[0] = (f32x4){0.f, 0.f, 0.f, 0.f};
  acc[1] = (f32x4){0.f, 0.f, 0.f, 0.f};
  #pragma unroll
  for (int kt = 0; kt < 16; ++kt) {
    bf16x8 a = *(const bf16x8*)(agg + (size_t)(mrow + l16) * 512 + kt * 32 + lk * 8);
    #pragma unroll
    for (int nn = 0; nn < 2; ++nn) {
      int ncol = (wave * 2 + nn) * 16 + l16;
      bf16x8 bfr = *(const bf16x8*)(WaggT + (size_t)ncol * 512 + kt * 32 + lk * 8);
      acc[nn] = __builtin_amdgcn_mfma_f32_16x16x32_bf16(a, bfr, acc[nn], 0, 0, 0);
    }
  }
  #pragma unroll
  for (int nn = 0; nn < 2; ++nn) {
    int col = (wave * 2 + nn) * 16 + l16;
    float bias = bagg[col];
    #pragma unroll
    for (int j = 0; j < 4; ++j) {
      int row = mrow + lk * 4 + j;
      out[row * 128 + col] = clone[row * 128 + col] + fmaxf(acc[nn][j] + bias, 0.f);
    }
  }
}

extern "C" void kernel_launch(void* const* d_in, const int* in_sizes, int n_in,
                              void* d_out, int out_size, void* d_ws, size_t ws_size,
                              hipStream_t stream) {
  const float* food  = (const float*)d_in[0];
  const float* trel  = (const float*)d_in[1];
  const float* clone = (const float*)d_in[2];
  const float* crel  = (const float*)d_in[3];
  const int*   tmask = (const int*)d_in[4];
  const int*   cmask = (const int*)d_in[5];
  const float* Wt    = (const float*)d_in[6];
  const float* bt    = (const float*)d_in[7];
  const float* Wc    = (const float*)d_in[8];
  const float* bcl   = (const float*)d_in[9];
  const float* Wa    = (const float*)d_in[10];
  const float* ba    = (const float*)d_in[11];
  float* out = (float*)d_out;

  char* w = (char*)d_ws;
  float* cpt = (float*)w;                      w += (size_t)BC * 128 * 4;
  float* cp1 = (float*)w;                      w += (size_t)BC * 128 * 4;
  unsigned short* W2T    = (unsigned short*)w; w += 128 * 128 * 2;
  unsigned short* WcombT = (unsigned short*)w; w += 128 * 256 * 2;
  unsigned short* WaggT  = (unsigned short*)w; w += 128 * 512 * 2;
  unsigned short* aggb   = (unsigned short*)w; w += (size_t)BC * 512 * 2;

  prep_weights<<<448, 256, 0, stream>>>(Wt, Wc, Wa, W2T, WcombT, WaggT);
  prep_rows<<<BC, 128, 0, stream>>>(clone, food, Wt, Wc, bt, bcl, cpt, cp1, aggb);
  branch_kernel<4, 256><<<BC, 256, 0, stream>>>(trel, clone, cpt, tmask, W2T, aggb);
  branch_kernel<8, 384><<<BC, 256, 0, stream>>>(crel, clone, cp1, cmask, WcombT, aggb);
  final_kernel<<<128, 256, 0, stream>>>(aggb, WaggT, clone, ba, out);
}

// Round 2
// 89.651 us; speedup vs baseline: 1.2574x; 1.2574x over previous
//
#include <hip/hip_runtime.h>

#define BB 16
#define CC 128
#define TT 128
#define HH 128
#define BC (BB*CC)   // 2048

typedef __attribute__((ext_vector_type(8))) short bf16x8;
typedef __attribute__((ext_vector_type(4))) float f32x4;

__device__ __forceinline__ unsigned short f2bf(float f) {
  union { float f; unsigned u; } v; v.f = f;
  unsigned u = v.u;
  u += 0x7FFFu + ((u >> 16) & 1u);   // round-to-nearest-even
  return (unsigned short)(u >> 16);
}

__device__ __forceinline__ bf16x8 pack8(float4 a, float4 b) {
  bf16x8 r;
  r[0] = (short)f2bf(a.x); r[1] = (short)f2bf(a.y);
  r[2] = (short)f2bf(a.z); r[3] = (short)f2bf(a.w);
  r[4] = (short)f2bf(b.x); r[5] = (short)f2bf(b.y);
  r[6] = (short)f2bf(b.z); r[7] = (short)f2bf(b.w);
  return r;
}

// ---------------- prep: weights to bf16, fragment-major swizzle -------------
// Fragment f = kt*8 + n, lane l, elem e:  value = W_src[k][ncol]
//   ncol = n*16 + (l&15),  k = kt*32 + (l>>4)*8 + e
// W2sw  (thorn): kt 0..3, src row = 128 + k          of W_thorn(256,128)
// Wcsw  (clone): kt 0..3 -> 256 + k (W3);  kt 4..7 -> 128 + (kt-4)*32+... (W2')
// WaggT (final): WaggT[n*512 + k] = W_agg[k*128 + n]
__global__ __launch_bounds__(256) void prep_weights(
    const float* __restrict__ Wt, const float* __restrict__ Wc, const float* __restrict__ Wa,
    unsigned short* __restrict__ W2sw, unsigned short* __restrict__ Wcsw,
    unsigned short* __restrict__ WaggT) {
  int i = blockIdx.x * 256 + threadIdx.x;
  if (i < 2048) {                       // thorn frags: 32 frags x 64 lanes
    int f = i >> 6, l = i & 63;
    int kt = f >> 3, n = f & 7;
    int ncol = n * 16 + (l & 15);
    int k0 = kt * 32 + (l >> 4) * 8;
    unsigned short out[8];
    #pragma unroll
    for (int e = 0; e < 8; ++e) out[e] = f2bf(Wt[(128 + k0 + e) * 128 + ncol]);
    *(uint4*)&W2sw[i * 8] = *(uint4*)out;
  } else if (i < 6144) {                // clone frags: 64 frags x 64 lanes
    int j = i - 2048;
    int f = j >> 6, l = j & 63;
    int kt = f >> 3, n = f & 7;
    int ncol = n * 16 + (l & 15);
    int lk8 = (l >> 4) * 8;
    unsigned short out[8];
    #pragma unroll
    for (int e = 0; e < 8; ++e) {
      int src = (kt < 4) ? (256 + kt * 32 + lk8 + e) : (128 + (kt - 4) * 32 + lk8 + e);
      out[e] = f2bf(Wc[src * 128 + ncol]);
    }
    *(uint4*)&Wcsw[j * 8] = *(uint4*)out;
  } else if (i < 14336) {               // agg weights: 8 k-elems per thread
    int j = i - 6144;                   // [0, 8192)
    int n = j >> 6, k0 = (j & 63) * 8;
    unsigned short out[8];
    #pragma unroll
    for (int e = 0; e < 8; ++e) out[e] = f2bf(Wa[(k0 + e) * 128 + n]);
    *(uint4*)&WaggT[n * 512 + k0] = *(uint4*)out;
  }
}

// -------- prep: bias rows (clone@W + b) and the easy agg slices --------
__global__ __launch_bounds__(128) void prep_rows(
    const float* __restrict__ clone, const float* __restrict__ food,
    const float* __restrict__ Wt, const float* __restrict__ Wc,
    const float* __restrict__ bt, const float* __restrict__ bcl,
    float* __restrict__ cpt, float* __restrict__ cp1,
    unsigned short* __restrict__ agg) {
  int bc = blockIdx.x; int k = threadIdx.x;
  __shared__ float cl[128];
  cl[k] = clone[bc * 128 + k];
  __syncthreads();
  float s1 = bt[k], s2 = bcl[k];
  #pragma unroll 8
  for (int h = 0; h < 128; ++h) {
    float c = cl[h];
    s1 = fmaf(c, Wt[h * 128 + k], s1);
    s2 = fmaf(c, Wc[h * 128 + k], s2);
  }
  cpt[bc * 128 + k] = s1;
  cp1[bc * 128 + k] = s2;
  agg[bc * 512 + k]       = f2bf(cl[k]);
  agg[bc * 512 + 128 + k] = f2bf(food[bc * 128 + k]);
}

// ---------------- branch kernel: persistent over 4 bc tiles -----------------
// 512 threads = 8 waves; wave w owns rows w*16..w*16+15.
// W staged once (fragment-major, conflict-free); A reg-double-buffered.
template<int NKT, int AGGOFF>
__global__ __launch_bounds__(512, 4) void branch2(
    const float* __restrict__ rel, const float* __restrict__ cloneA,
    const float* __restrict__ biasrow, const int* __restrict__ mask,
    const uint4* __restrict__ Wsw, unsigned short* __restrict__ agg) {
  __shared__ uint4 Wlds[NKT * 8 * 64];        // 32 KB (thorn) / 64 KB (clone)
  __shared__ float redbuf[8][128];

  const int tid = threadIdx.x;
  const int wave = tid >> 6, lane = tid & 63;
  const int l16 = lane & 15, lk = lane >> 4;
  const int bc0 = blockIdx.x << 2;
  const int b = bc0 >> 7;                     // same b for all 4 tiles (128%4==0)

  #pragma unroll
  for (int i = 0; i < NKT; ++i)               // NKT*512 uint4 total
    Wlds[i * 512 + tid] = Wsw[i * 512 + tid];

  // this thread's 4 output rows: row = wave*16 + lk*4 + j
  const int4 mk4 = *(const int4*)&mask[b * 128 + wave * 16 + lk * 4];
  const float mrow[4] = {(float)mk4.x, (float)mk4.y, (float)mk4.z, (float)mk4.w};

  // clone branch: K-extension fragments from clone[b] (rows = output rows), once
  bf16x8 afragC[4];
  if (NKT == 8) {
    const float* Cb = cloneA + ((size_t)b * 128 + wave * 16 + l16) * 128 + lk * 8;
    #pragma unroll
    for (int kt = 0; kt < 4; ++kt)
      afragC[kt] = pack8(*(const float4*)(Cb + kt * 32),
                         *(const float4*)(Cb + kt * 32 + 4));
  }

  // prefetch tile 0 (f32 in regs)
  const float* Rbase = rel + ((size_t)bc0 * 128 + wave * 16 + l16) * 128 + lk * 8;
  float4 pf[4][2];
  #pragma unroll
  for (int kt = 0; kt < 4; ++kt) {
    pf[kt][0] = *(const float4*)(Rbase + kt * 32);
    pf[kt][1] = *(const float4*)(Rbase + kt * 32 + 4);
  }

  __syncthreads();                            // W ready

  for (int t = 0; t < 4; ++t) {
    const int bc = bc0 + t;

    // convert this tile's A (loads drained by previous iteration's barrier)
    bf16x8 afragR[4];
    #pragma unroll
    for (int kt = 0; kt < 4; ++kt) afragR[kt] = pack8(pf[kt][0], pf[kt][1]);

    // issue next tile's loads: they fly during MFMA + epilogue
    if (t < 3) {
      const float* Rn = Rbase + (size_t)(t + 1) * 16384;
      #pragma unroll
      for (int kt = 0; kt < 4; ++kt) {
        pf[kt][0] = *(const float4*)(Rn + kt * 32);
        pf[kt][1] = *(const float4*)(Rn + kt * 32 + 4);
      }
    }
    float bias[8];
    #pragma unroll
    for (int n = 0; n < 8; ++n) bias[n] = biasrow[bc * 128 + n * 16 + l16];

    f32x4 acc[8];
    #pragma unroll
    for (int n = 0; n < 8; ++n) acc[n] = (f32x4){0.f, 0.f, 0.f, 0.f};
    #pragma unroll
    for (int kt = 0; kt < NKT; ++kt) {        // kt outer: 8 independent acc chains
      bf16x8 a = (kt < 4) ? afragR[kt] : afragC[kt - 4];
      #pragma unroll
      for (int n = 0; n < 8; ++n) {
        bf16x8 bfr = *(const bf16x8*)&Wlds[(kt * 8 + n) * 64 + lane];
        acc[n] = __builtin_amdgcn_mfma_f32_16x16x32_bf16(a, bfr, acc[n], 0, 0, 0);
      }
    }

    // epilogue: bias, relu, row-mask, max over 128 rows
    #pragma unroll
    for (int n = 0; n < 8; ++n) {
      float m0 = 0.f;
      #pragma unroll
      for (int j = 0; j < 4; ++j) {
        float x = fmaxf(acc[n][j] + bias[n], 0.f) * mrow[j];
        m0 = fmaxf(m0, x);
      }
      float v = fmaxf(m0, __shfl_xor(m0, 16));
      v = fmaxf(v, __shfl_xor(v, 32));
      if (lane < 16) redbuf[wave][n * 16 + lane] = v;
    }
    __syncthreads();
    if (tid < 128) {
      float v = redbuf[0][tid];
      #pragma unroll
      for (int w2 = 1; w2 < 8; ++w2) v = fmaxf(v, redbuf[w2][tid]);
      agg[(size_t)bc * 512 + AGGOFF + tid] = f2bf(v);
    }
    if (t < 3) __syncthreads();               // redbuf reuse guard
  }
}

// ---------------- final: out = clone + relu(agg(2048x512) @ W_agg + b_agg) --
__global__ __launch_bounds__(256) void final_kernel(
    const unsigned short* __restrict__ agg, const unsigned short* __restrict__ WaggT,
    const float* __restrict__ clone, const float* __restrict__ bagg,
    float* __restrict__ out) {
  const int tid = threadIdx.x;
  const int wave = tid >> 6, lane = tid & 63;
  const int l16 = lane & 15, lk = lane >> 4;
  const int mrow = blockIdx.x * 16;

  f32x4 acc[2];
  acc[0] = (f32x4){0.f, 0.f, 0.f, 0.f};
  acc[1] = (f32x4){0.f, 0.f, 0.f, 0.f};
  #pragma unroll
  for (int kt = 0; kt < 16; ++kt) {
    bf16x8 a = *(const bf16x8*)(agg + (size_t)(mrow + l16) * 512 + kt * 32 + lk * 8);
    #pragma unroll
    for (int nn = 0; nn < 2; ++nn) {
      int ncol = (wave * 2 + nn) * 16 + l16;
      bf16x8 bfr = *(const bf16x8*)(WaggT + (size_t)ncol * 512 + kt * 32 + lk * 8);
      acc[nn] = __builtin_amdgcn_mfma_f32_16x16x32_bf16(a, bfr, acc[nn], 0, 0, 0);
    }
  }
  #pragma unroll
  for (int nn = 0; nn < 2; ++nn) {
    int col = (wave * 2 + nn) * 16 + l16;
    float bias = bagg[col];
    #pragma unroll
    for (int j = 0; j < 4; ++j) {
      int row = mrow + lk * 4 + j;
      out[row * 128 + col] = clone[row * 128 + col] + fmaxf(acc[nn][j] + bias, 0.f);
    }
  }
}

extern "C" void kernel_launch(void* const* d_in, const int* in_sizes, int n_in,
                              void* d_out, int out_size, void* d_ws, size_t ws_size,
                              hipStream_t stream) {
  const float* food  = (const float*)d_in[0];
  const float* trel  = (const float*)d_in[1];
  const float* clone = (const float*)d_in[2];
  const float* crel  = (const float*)d_in[3];
  const int*   tmask = (const int*)d_in[4];
  const int*   cmask = (const int*)d_in[5];
  const float* Wt    = (const float*)d_in[6];
  const float* bt    = (const float*)d_in[7];
  const float* Wc    = (const float*)d_in[8];
  const float* bcl   = (const float*)d_in[9];
  const float* Wa    = (const float*)d_in[10];
  const float* ba    = (const float*)d_in[11];
  float* out = (float*)d_out;

  char* w = (char*)d_ws;
  float* cpt = (float*)w;                      w += (size_t)BC * 128 * 4;
  float* cp1 = (float*)w;                      w += (size_t)BC * 128 * 4;
  unsigned short* W2sw  = (unsigned short*)w;  w += 32 * 64 * 8 * 2;     // 32 KB
  unsigned short* Wcsw  = (unsigned short*)w;  w += 64 * 64 * 8 * 2;     // 64 KB
  unsigned short* WaggT = (unsigned short*)w;  w += 128 * 512 * 2;       // 128 KB
  unsigned short* aggb  = (unsigned short*)w;  w += (size_t)BC * 512 * 2;

  prep_weights<<<56, 256, 0, stream>>>(Wt, Wc, Wa, W2sw, Wcsw, WaggT);
  prep_rows<<<BC, 128, 0, stream>>>(clone, food, Wt, Wc, bt, bcl, cpt, cp1, aggb);
  branch2<4, 256><<<512, 512, 0, stream>>>(trel, clone, cpt, tmask, (const uint4*)W2sw, aggb);
  branch2<8, 384><<<512, 512, 0, stream>>>(crel, clone, cp1, cmask, (const uint4*)Wcsw, aggb);
  final_kernel<<<128, 256, 0, stream>>>(aggb, WaggT, clone, ba, out);
}

// Round 4
// 88.667 us; speedup vs baseline: 1.2714x; 1.0111x over previous
//
#include <hip/hip_runtime.h>

#define BB 16
#define CC 128
#define TT 128
#define HH 128
#define BC (BB*CC)   // 2048

typedef __attribute__((ext_vector_type(8))) short bf16x8;
typedef __attribute__((ext_vector_type(4))) float f32x4;

__device__ __forceinline__ unsigned short f2bf(float f) {
  union { float f; unsigned u; } v; v.f = f;
  unsigned u = v.u;
  u += 0x7FFFu + ((u >> 16) & 1u);   // round-to-nearest-even
  return (unsigned short)(u >> 16);
}

__device__ __forceinline__ bf16x8 pack8(f32x4 a, f32x4 b) {
  bf16x8 r;
  r[0] = (short)f2bf(a[0]); r[1] = (short)f2bf(a[1]);
  r[2] = (short)f2bf(a[2]); r[3] = (short)f2bf(a[3]);
  r[4] = (short)f2bf(b[0]); r[5] = (short)f2bf(b[1]);
  r[6] = (short)f2bf(b[2]); r[7] = (short)f2bf(b[3]);
  return r;
}

__device__ __forceinline__ f32x4 ntload(const float* p) {
  return __builtin_nontemporal_load((const f32x4*)p);
}

// ---------------- prep: weights (blocks 0..55) + bias rows (blocks 56..311) -
// Weight fragments are fragment-major: frag f = kt*8+n, lane l, elem e:
//   value = W_src[k][ncol],  ncol = n*16 + (l&15),  k = kt*32 + (l>>4)*8 + e
__global__ __launch_bounds__(256) void prep_kernel(
    const float* __restrict__ Wt, const float* __restrict__ Wc, const float* __restrict__ Wa,
    const float* __restrict__ clone, const float* __restrict__ food,
    const float* __restrict__ bt, const float* __restrict__ bcl,
    unsigned short* __restrict__ W2sw, unsigned short* __restrict__ Wcsw,
    unsigned short* __restrict__ WaggT,
    float* __restrict__ cpt, float* __restrict__ cp1,
    unsigned short* __restrict__ agg) {
  const int blk = blockIdx.x, tid = threadIdx.x;
  if (blk < 56) {
    int i = blk * 256 + tid;
    if (i < 2048) {                       // thorn frags: 32 frags x 64 lanes
      int f = i >> 6, l = i & 63;
      int kt = f >> 3, n = f & 7;
      int ncol = n * 16 + (l & 15);
      int k0 = kt * 32 + (l >> 4) * 8;
      unsigned short o[8];
      #pragma unroll
      for (int e = 0; e < 8; ++e) o[e] = f2bf(Wt[(128 + k0 + e) * 128 + ncol]);
      *(uint4*)&W2sw[i * 8] = *(uint4*)o;
    } else if (i < 6144) {                // clone frags: 64 frags x 64 lanes
      int j = i - 2048;
      int f = j >> 6, l = j & 63;
      int kt = f >> 3, n = f & 7;
      int ncol = n * 16 + (l & 15);
      int lk8 = (l >> 4) * 8;
      unsigned short o[8];
      #pragma unroll
      for (int e = 0; e < 8; ++e) {
        int src = (kt < 4) ? (256 + kt * 32 + lk8 + e) : (128 + (kt - 4) * 32 + lk8 + e);
        o[e] = f2bf(Wc[src * 128 + ncol]);
      }
      *(uint4*)&Wcsw[j * 8] = *(uint4*)o;
    } else if (i < 14336) {               // agg weights, plain [n][k] transpose
      int j = i - 6144;                   // [0, 8192)
      int n = j >> 6, k0 = (j & 63) * 8;
      unsigned short o[8];
      #pragma unroll
      for (int e = 0; e < 8; ++e) o[e] = f2bf(Wa[(k0 + e) * 128 + n]);
      *(uint4*)&WaggT[n * 512 + k0] = *(uint4*)o;
    }
  } else {
    // bias rows: 8 bc rows per block; weight reads amortized 8x (32 MB L2 total)
    const int bc0 = (blk - 56) * 8;
    __shared__ float cl[8][128];
    for (int i = tid; i < 1024; i += 256) cl[i >> 7][i & 127] = clone[bc0 * 128 + i];
    __syncthreads();
    const int k = tid & 127, r0 = (tid >> 7) * 4;
    float s1[4], s2[4];
    #pragma unroll
    for (int r = 0; r < 4; ++r) { s1[r] = bt[k]; s2[r] = bcl[k]; }
    #pragma unroll 8
    for (int h = 0; h < 128; ++h) {
      float w1 = Wt[h * 128 + k], w2 = Wc[h * 128 + k];
      #pragma unroll
      for (int r = 0; r < 4; ++r) {
        float c = cl[r0 + r][h];
        s1[r] = fmaf(c, w1, s1[r]);
        s2[r] = fmaf(c, w2, s2[r]);
      }
    }
    #pragma unroll
    for (int r = 0; r < 4; ++r) {
      cpt[(bc0 + r0 + r) * 128 + k] = s1[r];
      cp1[(bc0 + r0 + r) * 128 + k] = s2[r];
    }
    for (int i = tid; i < 1024; i += 256) {
      int r = i >> 7, kk = i & 127;
      agg[(size_t)(bc0 + r) * 512 + kk]       = f2bf(cl[r][kk]);
      agg[(size_t)(bc0 + r) * 512 + 128 + kk] = f2bf(food[bc0 * 128 + i]);
    }
  }
}

// ---------------- fused branch kernel: blocks 0..511 clone, 512..1023 thorn -
// 512 threads = 8 waves; wave w owns rows w*16..w*16+15; 4 bc tiles per block.
// W staged once (fragment-major, conflict-free); A reg-double-buffered.
__global__ __launch_bounds__(512, 4) void branch3(
    const float* __restrict__ trel, const float* __restrict__ crel,
    const float* __restrict__ cloneA,
    const float* __restrict__ cpt, const float* __restrict__ cp1,
    const int* __restrict__ tmask, const int* __restrict__ cmask,
    const uint4* __restrict__ W2sw, const uint4* __restrict__ Wcsw,
    unsigned short* __restrict__ agg) {
  __shared__ uint4 Wlds[8 * 512];             // 64 KB
  __shared__ float redbuf[2][8][128];         // 8 KB, double-buffered

  const bool isClone = blockIdx.x < 512;
  const int tileIdx = blockIdx.x & 511;
  const float* __restrict__ rel     = isClone ? crel  : trel;
  const float* __restrict__ biasrow = isClone ? cp1   : cpt;
  const int*   __restrict__ mask    = isClone ? cmask : tmask;
  const uint4* __restrict__ Wsw     = isClone ? Wcsw  : W2sw;
  const int aggoff = isClone ? 384 : 256;
  const int nkt    = isClone ? 8 : 4;

  const int tid = threadIdx.x;
  const int wave = tid >> 6, lane = tid & 63;
  const int l16 = lane & 15, lk = lane >> 4;
  const int bc0 = tileIdx << 2;
  const int b = bc0 >> 7;                     // same b for all 4 tiles

  for (int i = tid; i < nkt * 512; i += 512)
    Wlds[i] = Wsw[i];

  // this thread's 4 output rows: row = wave*16 + lk*4 + j
  const int4 mk4 = *(const int4*)&mask[b * 128 + wave * 16 + lk * 4];
  const float mrow[4] = {(float)mk4.x, (float)mk4.y, (float)mk4.z, (float)mk4.w};

  // clone branch: K-extension fragments from clone[b] (rows = output rows)
  bf16x8 afragC[4];
  if (isClone) {
    const float* Cb = cloneA + ((size_t)b * 128 + wave * 16 + l16) * 128 + lk * 8;
    #pragma unroll
    for (int kt = 0; kt < 4; ++kt)
      afragC[kt] = pack8(*(const f32x4*)(Cb + kt * 32),
                         *(const f32x4*)(Cb + kt * 32 + 4));
  }

  // prefetch tile 0 (f32 in regs, nontemporal: relations have zero reuse)
  const float* Rbase = rel + ((size_t)bc0 * 128 + wave * 16 + l16) * 128 + lk * 8;
  f32x4 pf[4][2];
  #pragma unroll
  for (int kt = 0; kt < 4; ++kt) {
    pf[kt][0] = ntload(Rbase + kt * 32);
    pf[kt][1] = ntload(Rbase + kt * 32 + 4);
  }

  __syncthreads();                            // W ready

  for (int t = 0; t < 4; ++t) {
    const int bc = bc0 + t;

    bf16x8 afragR[4];
    #pragma unroll
    for (int kt = 0; kt < 4; ++kt) afragR[kt] = pack8(pf[kt][0], pf[kt][1]);

    // issue next tile's loads: they fly during MFMA + epilogue
    if (t < 3) {
      const float* Rn = Rbase + (size_t)(t + 1) * 16384;
      #pragma unroll
      for (int kt = 0; kt < 4; ++kt) {
        pf[kt][0] = ntload(Rn + kt * 32);
        pf[kt][1] = ntload(Rn + kt * 32 + 4);
      }
    }
    float bias[8];
    #pragma unroll
    for (int n = 0; n < 8; ++n) bias[n] = biasrow[bc * 128 + n * 16 + l16];

    f32x4 acc[8];
    #pragma unroll
    for (int n = 0; n < 8; ++n) acc[n] = (f32x4){0.f, 0.f, 0.f, 0.f};
    #pragma unroll
    for (int kt = 0; kt < 4; ++kt) {
      #pragma unroll
      for (int n = 0; n < 8; ++n) {
        bf16x8 bfr = *(const bf16x8*)&Wlds[(kt * 8 + n) * 64 + lane];
        acc[n] = __builtin_amdgcn_mfma_f32_16x16x32_bf16(afragR[kt], bfr, acc[n], 0, 0, 0);
      }
    }
    if (isClone) {
      #pragma unroll
      for (int kt = 0; kt < 4; ++kt) {
        #pragma unroll
        for (int n = 0; n < 8; ++n) {
          bf16x8 bfr = *(const bf16x8*)&Wlds[((kt + 4) * 8 + n) * 64 + lane];
          acc[n] = __builtin_amdgcn_mfma_f32_16x16x32_bf16(afragC[kt], bfr, acc[n], 0, 0, 0);
        }
      }
    }

    // epilogue: bias, relu, row-mask, max over 128 rows
    #pragma unroll
    for (int n = 0; n < 8; ++n) {
      float m0 = 0.f;
      #pragma unroll
      for (int j = 0; j < 4; ++j) {
        float x = fmaxf(acc[n][j] + bias[n], 0.f) * mrow[j];
        m0 = fmaxf(m0, x);
      }
      float v = fmaxf(m0, __shfl_xor(m0, 16));
      v = fmaxf(v, __shfl_xor(v, 32));
      if (lane < 16) redbuf[t & 1][wave][n * 16 + lane] = v;
    }
    __syncthreads();
    if (tid < 128) {
      float v = redbuf[t & 1][0][tid];
      #pragma unroll
      for (int w2 = 1; w2 < 8; ++w2) v = fmaxf(v, redbuf[t & 1][w2][tid]);
      agg[(size_t)bc * 512 + aggoff + tid] = f2bf(v);
    }
    // no second barrier: next tile writes the other redbuf half
  }
}

// ---------------- final: out = clone + relu(agg(2048x512) @ W_agg + b_agg) --
__global__ __launch_bounds__(256) void final_kernel(
    const unsigned short* __restrict__ agg, const unsigned short* __restrict__ WaggT,
    const float* __restrict__ clone, const float* __restrict__ bagg,
    float* __restrict__ out) {
  const int tid = threadIdx.x;
  const int wave = tid >> 6, lane = tid & 63;
  const int l16 = lane & 15, lk = lane >> 4;
  const int mrow = blockIdx.x * 16;

  f32x4 acc[2];
  acc[0] = (f32x4){0.f, 0.f, 0.f, 0.f};
  acc[1] = (f32x4){0.f, 0.f, 0.f, 0.f};
  #pragma unroll
  for (int kt = 0; kt < 16; ++kt) {
    bf16x8 a = *(const bf16x8*)(agg + (size_t)(mrow + l16) * 512 + kt * 32 + lk * 8);
    #pragma unroll
    for (int nn = 0; nn < 2; ++nn) {
      int ncol = (wave * 2 + nn) * 16 + l16;
      bf16x8 bfr = *(const bf16x8*)(WaggT + (size_t)ncol * 512 + kt * 32 + lk * 8);
      acc[nn] = __builtin_amdgcn_mfma_f32_16x16x32_bf16(a, bfr, acc[nn], 0, 0, 0);
    }
  }
  #pragma unroll
  for (int nn = 0; nn < 2; ++nn) {
    int col = (wave * 2 + nn) * 16 + l16;
    float bias = bagg[col];
    #pragma unroll
    for (int j = 0; j < 4; ++j) {
      int row = mrow + lk * 4 + j;
      out[row * 128 + col] = clone[row * 128 + col] + fmaxf(acc[nn][j] + bias, 0.f);
    }
  }
}

extern "C" void kernel_launch(void* const* d_in, const int* in_sizes, int n_in,
                              void* d_out, int out_size, void* d_ws, size_t ws_size,
                              hipStream_t stream) {
  const float* food  = (const float*)d_in[0];
  const float* trel  = (const float*)d_in[1];
  const float* clone = (const float*)d_in[2];
  const float* crel  = (const float*)d_in[3];
  const int*   tmask = (const int*)d_in[4];
  const int*   cmask = (const int*)d_in[5];
  const float* Wt    = (const float*)d_in[6];
  const float* bt    = (const float*)d_in[7];
  const float* Wc    = (const float*)d_in[8];
  const float* bcl   = (const float*)d_in[9];
  const float* Wa    = (const float*)d_in[10];
  const float* ba    = (const float*)d_in[11];
  float* out = (float*)d_out;

  char* w = (char*)d_ws;
  float* cpt = (float*)w;                      w += (size_t)BC * 128 * 4;
  float* cp1 = (float*)w;                      w += (size_t)BC * 128 * 4;
  unsigned short* W2sw  = (unsigned short*)w;  w += 32 * 64 * 8 * 2;     // 32 KB
  unsigned short* Wcsw  = (unsigned short*)w;  w += 64 * 64 * 8 * 2;     // 64 KB
  unsigned short* WaggT = (unsigned short*)w;  w += 128 * 512 * 2;       // 128 KB
  unsigned short* aggb  = (unsigned short*)w;  w += (size_t)BC * 512 * 2;

  prep_kernel<<<312, 256, 0, stream>>>(Wt, Wc, Wa, clone, food, bt, bcl,
                                       W2sw, Wcsw, WaggT, cpt, cp1, aggb);
  branch3<<<1024, 512, 0, stream>>>(trel, crel, clone, cpt, cp1, tmask, cmask,
                                    (const uint4*)W2sw, (const uint4*)Wcsw, aggb);
  final_kernel<<<128, 256, 0, stream>>>(aggb, WaggT, clone, ba, out);
}